// Round 9
// baseline (1571.392 us; speedup 1.0000x reference)
//
#include <hip/hip_runtime.h>
#include <hip/hip_bf16.h>
#include <hip/hip_cooperative_groups.h>

namespace cg = cooperative_groups;

#define DFEAT 128
#define WPAD 136

typedef _Float16 h2 __attribute__((ext_vector_type(2)));
typedef _Float16 f16x8 __attribute__((ext_vector_type(8)));
typedef float f32x4  __attribute__((ext_vector_type(4)));
typedef unsigned short u16x8 __attribute__((ext_vector_type(8)));

__device__ __forceinline__ unsigned short f16b(float f) {
    _Float16 hf = (_Float16)f;
    unsigned short b; __builtin_memcpy(&b, &hf, 2);
    return b;
}
__device__ __forceinline__ unsigned pack_f16(float lo, float hi) {
    return (unsigned)f16b(lo) | ((unsigned)f16b(hi) << 16);
}
__device__ __forceinline__ float h2f(h2 v) { float f; __builtin_memcpy(&f, &v, 4); return f; }
__device__ __forceinline__ h2 f2h(float f) { h2 v; __builtin_memcpy(&v, &f, 4); return v; }

// Chebyshev algebra folded into weights (fp32, at prep):
//   out = h@(W0 - W2) + Tx1@W1 + P@(2*W2),  P = L_hat @ Tx1
// -> both props are identical pure gathers.
//
// Round-8 conclusion: the gather has an invariant ~30-40us floor across every
// lane geometry / dtype / slicing variant -> L2-miss service rate
// (MSHR x LLC latency) bound, occupancy-insensitive. The remaining big cost
// is ~130us of launch/join overhead across 14 dispatches (~10us each).
// Round-9: ONE cooperative kernel, grid.sync() between phases.

// ---------------- prop phase: hout = L_hat @ hin (16B lanes, 32 slots/iter) ----------------
__device__ __forceinline__ void prop_phase(
    const unsigned* __restrict__ hin, unsigned* __restrict__ hout,
    const int* __restrict__ row_ptr, const unsigned* __restrict__ e_cw,
    int n, int lane, int gwave, int ngwave)
{
    const uint4* __restrict__ hin4 = (const uint4*)hin;
    const int e2 = lane >> 4;      // edge within 4-pack (0..3)
    const int s  = lane & 15;      // 16B segment (features 8s..8s+7)
    for (int node = gwave; node < n; node += ngwave) {
        int rs = row_ptr[node];
        int re = row_ptr[node + 1];
        h2 a0 = (h2){(_Float16)0.f, (_Float16)0.f};
        h2 a1 = a0, a2 = a0, a3 = a0;
        for (int j = rs; j < re; j += 32) {
            uint4 vv[8]; unsigned ww[8];
            #pragma unroll
            for (int u = 0; u < 8; ++u) {
                int i0 = j + 4 * u;
                unsigned c0 = (i0     < re) ? e_cw[i0]     : 0u;  // uniform -> s_load
                unsigned c1 = (i0 + 1 < re) ? e_cw[i0 + 1] : 0u;
                unsigned c2 = (i0 + 2 < re) ? e_cw[i0 + 2] : 0u;
                unsigned c3 = (i0 + 3 < re) ? e_cw[i0 + 3] : 0u;
                unsigned cw = (e2 == 0) ? c0 : (e2 == 1) ? c1 : (e2 == 2) ? c2 : c3;
                ww[u] = (cw & 0xffff0000u) | (cw >> 16);          // (w,w) f16 pair
                vv[u] = hin4[(size_t)(cw & 0xffffu) * 16 + s];
            }
            #pragma unroll
            for (int u = 0; u < 8; ++u) {
                h2 wp = f2h(__uint_as_float(ww[u]));
                a0 = f2h(__uint_as_float(vv[u].x)) * wp + a0;     // v_pk_fma_f16
                a1 = f2h(__uint_as_float(vv[u].y)) * wp + a1;
                a2 = f2h(__uint_as_float(vv[u].z)) * wp + a2;
                a3 = f2h(__uint_as_float(vv[u].w)) * wp + a3;
            }
        }
        #pragma unroll
        for (int off = 16; off < 64; off <<= 1) {
            a0 = a0 + f2h(__shfl_xor(h2f(a0), off));
            a1 = a1 + f2h(__shfl_xor(h2f(a1), off));
            a2 = a2 + f2h(__shfl_xor(h2f(a2), off));
            a3 = a3 + f2h(__shfl_xor(h2f(a3), off));
        }
        if (e2 == 0) {
            uint4 o;
            o.x = __float_as_uint(h2f(a0));
            o.y = __float_as_uint(h2f(a1));
            o.z = __float_as_uint(h2f(a2));
            o.w = __float_as_uint(h2f(a3));
            ((uint4*)hout)[(size_t)node * 16 + s] = o;
        }
    }
}

// ---------------- the whole pipeline as ONE cooperative kernel ----------------
__global__ __launch_bounds__(256, 4) void cheb_mega_kernel(
    const float* __restrict__ x, const int* __restrict__ ei,
    const float* __restrict__ W1, const float* __restrict__ b1,
    const float* __restrict__ W2, const float* __restrict__ b2,
    const float* __restrict__ W3, const float* __restrict__ b3,
    float* __restrict__ out,
    unsigned* __restrict__ xb, unsigned* __restrict__ t1b,
    unsigned* __restrict__ t2b, unsigned* __restrict__ ab,
    unsigned short* __restrict__ wt, int* __restrict__ deg8,
    int* __restrict__ poff, int* __restrict__ row_ptr,
    float* __restrict__ dinv, unsigned* __restrict__ e_cw,
    int* __restrict__ csum, int N, int E)
{
    cg::grid_group grid = cg::this_grid();
    __shared__ unsigned short Ws[DFEAT * WPAD];   // 34816 B (gemm staging)

    const int t = threadIdx.x;
    const int tid = blockIdx.x * 256 + t;
    const int nthreads = gridDim.x * 256;
    const int lane = t & 63;
    const int wv = t >> 6;
    const int gwave = blockIdx.x * 4 + wv;
    const int ngwave = gridDim.x * 4;

    // ---- phase 0: zero deg8 + pack x->f16 + fold W->transposed f16 ----
    const int NPK = N * (DFEAT / 2);
    for (int i = tid; i < 8 * N; i += nthreads) deg8[i] = 0;
    for (int i = tid; i < NPK; i += nthreads) {
        float2 v = ((const float2*)x)[i];
        xb[i] = pack_f16(v.x, v.y);
    }
    const int PER = 3 * DFEAT * DFEAT;
    for (int i = tid; i < 3 * PER; i += nthreads) {
        int layer = i / PER;
        int rem = i - layer * PER;
        const float* W = (layer == 0) ? W1 : ((layer == 1) ? W2 : W3);
        int seg = rem >> 14;
        int k   = (rem >> 7) & 127;
        int nn  = rem & 127;
        float w = W[rem];
        if (seg == 0) w -= W[rem + 2 * DFEAT * DFEAT];   // W0' = W0 - W2
        else if (seg == 2) w *= 2.f;                      // W2' = 2*W2
        wt[layer * PER + (seg << 14) + (nn << 7) + k] = f16b(w);
    }
    grid.sync();

    // ---- phase 1: degree count (partitioned by edge-index bits) ----
    for (int e = tid; e < E; e += nthreads) {
        int r = ei[e];
        int c = ei[E + e];
        if (r != c) atomicAdd(&deg8[((e >> 8) & 7) * N + r], 1);
    }
    grid.sync();

    // ---- phase 2: per-64-node chunks: totals, poff, dinv, chunk-local scan ----
    const int NCH = (N + 63) / 64;
    for (int w = gwave; w < NCH; w += ngwave) {
        int node = w * 64 + lane;
        int tot = 0;
        if (node < N) {
            int run = 0;
            #pragma unroll
            for (int p = 0; p < 8; ++p) {
                int d = deg8[p * N + node];
                poff[p * N + node] = run;   // partition start; doubles as fill cursor
                run += d;
            }
            tot = run;
            dinv[node] = (tot > 0) ? rsqrtf((float)tot) : 0.f;
        }
        int vi = tot;
        #pragma unroll
        for (int off = 1; off < 64; off <<= 1) {
            int xx = __shfl_up(vi, off);
            if (lane >= off) vi += xx;
        }
        if (node < N) row_ptr[node + 1] = vi;   // chunk-local inclusive prefix
        if (lane == 63) csum[w] = vi;           // chunk total
    }
    grid.sync();

    // ---- phase 3: exclusive scan of chunk totals (one wave) ----
    if (blockIdx.x == 0 && t < 64) {
        int carry = 0;
        for (int base = 0; base < NCH; base += 64) {
            int v = (base + t < NCH) ? csum[base + t] : 0;
            int vi = v;
            #pragma unroll
            for (int off = 1; off < 64; off <<= 1) {
                int xx = __shfl_up(vi, off);
                if (t >= off) vi += xx;
            }
            if (base + t < NCH) csum[base + t] = carry + vi - v;
            carry += __shfl(vi, 63);
        }
    }
    grid.sync();

    // ---- phase 4: add chunk offsets -> final row_ptr ----
    for (int i = tid; i < N; i += nthreads) {
        if (i == 0) row_ptr[0] = 0;
        row_ptr[i + 1] += csum[i >> 6];
    }
    grid.sync();

    // ---- phase 5: CSR fill (col:u16 | w:f16) ----
    for (int e = tid; e < E; e += nthreads) {
        int r = ei[e];
        int c = ei[E + e];
        if (r != c) {
            int p = (e >> 8) & 7;   // must match phase-1 partitioning
            int k = atomicAdd(&poff[p * N + r], 1);
            int pos = row_ptr[r] + k;
            float w = -dinv[r] * dinv[c];
            e_cw[pos] = (unsigned)c | ((unsigned)f16b(w) << 16);
        }
    }
    grid.sync();

    // ---- 3 layers: prop1, prop2, fused 3-seg MFMA gemm ----
    const unsigned* hin = xb;
    const int quad = lane >> 4;
    const int l16  = lane & 15;
    const int NT = (N + 63) / 64;   // 64-row gemm tiles

    for (int l = 0; l < 3; ++l) {
        prop_phase(hin, t1b, row_ptr, e_cw, N, lane, gwave, ngwave);
        grid.sync();
        prop_phase(t1b, t2b, row_ptr, e_cw, N, lane, gwave, ngwave);
        grid.sync();

        const unsigned short* Wtl = wt + l * PER;
        const float* bias = (l == 0) ? b1 : (l == 1) ? b2 : b3;
        const unsigned short* X0 = (const unsigned short*)hin;
        const unsigned short* X1 = (const unsigned short*)t1b;
        const unsigned short* X2 = (const unsigned short*)t2b;
        const int srow  = t >> 1;           // staging: row 0..127
        const int shalf = (t & 1) * 64;     // half-row

        for (int vb = blockIdx.x; vb < NT; vb += gridDim.x) {
            int r0 = vb * 64 + wv * 16 + l16;
            if (r0 >= N) r0 = N - 1;

            f32x4 acc[8];
            #pragma unroll
            for (int c = 0; c < 8; ++c) acc[c] = (f32x4){0.f, 0.f, 0.f, 0.f};

            #pragma unroll
            for (int seg = 0; seg < 3; ++seg) {
                __syncthreads();   // previous seg fully consumed
                const unsigned short* Wp = Wtl + (seg << 14);
                #pragma unroll
                for (int i = 0; i < 8; ++i) {
                    *(u16x8*)&Ws[srow * WPAD + shalf + i * 8] =
                        *(const u16x8*)&Wp[srow * DFEAT + shalf + i * 8];
                }
                __syncthreads();
                const unsigned short* A =
                    ((seg == 0) ? X0 : (seg == 1) ? X1 : X2) + (size_t)r0 * DFEAT;
                #pragma unroll
                for (int kk = 0; kk < 4; ++kk) {
                    const int ko = kk * 32 + quad * 8;
                    f16x8 a = *(const f16x8*)(A + ko);
                    #pragma unroll
                    for (int c = 0; c < 8; ++c) {
                        f16x8 b = *(const f16x8*)&Ws[(c * 16 + l16) * WPAD + ko];
                        acc[c] = __builtin_amdgcn_mfma_f32_16x16x32_f16(a, b, acc[c], 0, 0, 0);
                    }
                }
            }

            // C/D layout: col = lane&15, row = quad*4 + reg
            const int orow0 = vb * 64 + wv * 16 + quad * 4;
            #pragma unroll
            for (int c = 0; c < 8; ++c) {
                const int col = c * 16 + l16;
                const float bv = bias[col];
                #pragma unroll
                for (int r = 0; r < 4; ++r) {
                    const int orow = orow0 + r;
                    if (orow < N) {
                        float v = fmaxf(acc[c][r] + bv, 0.f);
                        if (l < 2)
                            ((unsigned short*)ab)[(size_t)orow * DFEAT + col] = f16b(v);
                        else
                            out[(size_t)orow * DFEAT + col] = v;
                    }
                }
            }
        }
        if (l < 2) grid.sync();   // ab complete before next layer's prop1
        hin = ab;
    }
}

extern "C" void kernel_launch(void* const* d_in, const int* in_sizes, int n_in,
                              void* d_out, int out_size, void* d_ws, size_t ws_size,
                              hipStream_t stream) {
    const float* x  = (const float*)d_in[0];
    const int*   ei = (const int*)d_in[1];
    const float* W1 = (const float*)d_in[2];
    const float* b1 = (const float*)d_in[3];
    const float* W2 = (const float*)d_in[4];
    const float* b2 = (const float*)d_in[5];
    const float* W3 = (const float*)d_in[6];
    const float* b3 = (const float*)d_in[7];

    int N = in_sizes[0] / DFEAT;   // 50000
    int E = in_sizes[1] / 2;       // 800000
    const int NPK = N * (DFEAT / 2);

    // workspace layout
    unsigned* xb  = (unsigned*)d_ws;
    unsigned* t1b = xb  + NPK;
    unsigned* t2b = t1b + NPK;
    unsigned* ab  = t2b + NPK;
    unsigned short* wt = (unsigned short*)(ab + NPK);   // 3 layers * 3*128*128
    int*   deg8    = (int*)(wt + 3 * 3 * DFEAT * DFEAT);
    int*   poff    = deg8 + 8 * N;
    int*   row_ptr = poff + 8 * N;
    float* dinv    = (float*)(row_ptr + (N + 2));
    unsigned* e_cw = (unsigned*)(dinv + N);
    int*   csum    = (int*)(e_cw + E);                  // (N+63)/64 entries

    float* outp = (float*)d_out;

    static int grid_blocks = 0;
    if (grid_blocks == 0) {
        int nb = 0;
        hipOccupancyMaxActiveBlocksPerMultiprocessor(&nb, (const void*)cheb_mega_kernel, 256, 0);
        if (nb < 1) nb = 1;
        long g = (long)nb * 256;           // 256 CUs on MI355X
        grid_blocks = (int)((g > 1024) ? 1024 : g);
    }

    void* args[] = {
        (void*)&x, (void*)&ei,
        (void*)&W1, (void*)&b1, (void*)&W2, (void*)&b2, (void*)&W3, (void*)&b3,
        (void*)&outp,
        (void*)&xb, (void*)&t1b, (void*)&t2b, (void*)&ab,
        (void*)&wt, (void*)&deg8, (void*)&poff, (void*)&row_ptr,
        (void*)&dinv, (void*)&e_cw, (void*)&csum,
        (void*)&N, (void*)&E
    };
    hipLaunchCooperativeKernel((const void*)cheb_mega_kernel,
                               dim3(grid_blocks), dim3(256), args, 0, stream);
}

// Round 10
// 733.973 us; speedup vs baseline: 2.1409x; 2.1409x over previous
//
#include <hip/hip_runtime.h>
#include <hip/hip_bf16.h>

#define DFEAT 128

typedef _Float16 h2 __attribute__((ext_vector_type(2)));
typedef _Float16 f16x8 __attribute__((ext_vector_type(8)));
typedef float f32x4  __attribute__((ext_vector_type(4)));
typedef unsigned short u16x8 __attribute__((ext_vector_type(8)));

__device__ __forceinline__ unsigned short f16b(float f) {
    _Float16 hf = (_Float16)f;
    unsigned short b; __builtin_memcpy(&b, &hf, 2);
    return b;
}
__device__ __forceinline__ unsigned pack_f16(float lo, float hi) {
    return (unsigned)f16b(lo) | ((unsigned)f16b(hi) << 16);
}
__device__ __forceinline__ float h2f(h2 v) { float f; __builtin_memcpy(&f, &v, 4); return f; }
__device__ __forceinline__ h2 f2h(float f) { h2 v; __builtin_memcpy(&v, &f, 4); return v; }

// Chebyshev algebra folded into weights (fp32, at prep):
//   out = h@(W0 - W2) + Tx1@W1 + P@(2*W2),  P = L_hat @ Tx1
// -> both props are identical pure gathers.
//
// XCD-CONCURRENT SLICED layout [8][N][16 feats] (32 B per node per slice):
// prop blocks with slice = blockIdx&7 land on one XCD each (round-robin
// dispatch), so each XCD's gather table is 1.6 MB -> L2-resident. This cuts
// the r8-measured 91 MB/prop TCC-miss traffic (= 12.8 MB table x 8 XCD
// compulsory replication) without r6's serial-pass overhead: all 8 slices
// run concurrently. Feature-wise independence makes the slicing exact.

// ---------------- conv (FIRST): zero deg8 + x->f16 sliced pack + W->folded transposed f16 ------
__global__ void conv_kernel(const float2* __restrict__ x, unsigned* __restrict__ xb, int npk,
                            const float* __restrict__ W1, const float* __restrict__ W2,
                            const float* __restrict__ W3, unsigned short* __restrict__ Wt,
                            int* __restrict__ deg8, int N) {
    int id = blockIdx.x * blockDim.x + threadIdx.x;
    int gstride = gridDim.x * blockDim.x;
    for (int i = id; i < 8 * N; i += gstride) deg8[i] = 0;
    if (id < npk) {
        float2 v = x[id];
        int node = id >> 6;          // 64 float2 per node
        int p    = id & 63;          // feature pair (2p, 2p+1)
        // slice = p>>3 (16 feats each), word-in-slice = p&7
        xb[((size_t)(p >> 3) * N + node) * 8 + (p & 7)] = pack_f16(v.x, v.y);
        return;
    }
    int id2 = id - npk;
    const int PER = 3 * DFEAT * DFEAT;
    if (id2 < 3 * PER) {
        int layer = id2 / PER;
        int rem = id2 - layer * PER;
        const float* W = (layer == 0) ? W1 : ((layer == 1) ? W2 : W3);
        int seg = rem >> 14;
        int k   = (rem >> 7) & 127;
        int nn  = rem & 127;
        float w = W[rem];
        if (seg == 0) w -= W[rem + 2 * DFEAT * DFEAT];   // W0' = W0 - W2
        else if (seg == 2) w *= 2.f;                      // W2' = 2*W2
        Wt[layer * PER + (seg << 14) + (nn << 7) + k] = f16b(w);
    }
}

// ---------------- degree count (XCD-privatized, fire-and-forget atomics) ----------------
__global__ void deg_kernel(const int* __restrict__ ei, int* __restrict__ deg8, int E, int N) {
    int e = blockIdx.x * blockDim.x + threadIdx.x;
    if (e < E) {
        int r = ei[e];
        int c = ei[E + e];
        if (r != c) atomicAdd(&deg8[(blockIdx.x & 7) * N + r], 1);
    }
}

// ---------------- scan stage 1: partition prefix -> poff, totals -> dinv, block scan ----------------
__global__ __launch_bounds__(1024) void scan1_kernel(const int* __restrict__ deg8,
                                                     int* __restrict__ poff,
                                                     int* __restrict__ row_ptr,
                                                     int* __restrict__ bsum,
                                                     float* __restrict__ dinv, int n) {
    __shared__ int wsums[16];
    int t = threadIdx.x;
    int idx = blockIdx.x * 1024 + t;
    int tot = 0;
    if (idx < n) {
        int run = 0;
        #pragma unroll
        for (int p = 0; p < 8; ++p) {
            int d = deg8[p * n + idx];
            poff[p * n + idx] = run;   // partition start within row; doubles as fill cursor
            run += d;
        }
        tot = run;
        dinv[idx] = (tot > 0) ? rsqrtf((float)tot) : 0.f;
    }
    int vi = tot;
    #pragma unroll
    for (int off = 1; off < 64; off <<= 1) {
        int x = __shfl_up(vi, off);
        if ((t & 63) >= off) vi += x;
    }
    if ((t & 63) == 63) wsums[t >> 6] = vi;
    __syncthreads();
    if (t < 16) {
        int s = wsums[t];
        int si = s;
        #pragma unroll
        for (int off = 1; off < 16; off <<= 1) {
            int x = __shfl_up(si, off);
            if (t >= off) si += x;
        }
        wsums[t] = si - s;
        if (t == 15) bsum[blockIdx.x] = si;   // block total
    }
    __syncthreads();
    if (idx < n) row_ptr[idx + 1] = wsums[t >> 6] + vi;
}

// ---------------- scan stage 2+3 merged: each block reduces its bsum prefix itself ----------------
__global__ __launch_bounds__(1024) void scan3_kernel(int* __restrict__ row_ptr,
                                                     const int* __restrict__ bsum, int n) {
    __shared__ int soff;
    int t = threadIdx.x;
    if (t < 64) {
        int v = 0;
        for (int k = t; k < (int)blockIdx.x; k += 64) v += bsum[k];
        #pragma unroll
        for (int off = 32; off > 0; off >>= 1) v += __shfl_down(v, off);
        if (t == 0) soff = v;
    }
    __syncthreads();
    int idx = blockIdx.x * 1024 + t;
    if (idx == 0) row_ptr[0] = 0;
    if (idx < n) row_ptr[idx + 1] += soff;
}

// ---------------- CSR fill: packed (col:u16 | w:f16); poff doubles as cursor ----------------
__global__ void fill_kernel(const int* __restrict__ ei, const int* __restrict__ row_ptr,
                            int* __restrict__ poff, const float* __restrict__ dinv,
                            unsigned* __restrict__ e_cw, int E, int N) {
    int e = blockIdx.x * blockDim.x + threadIdx.x;
    if (e < E) {
        int r = ei[e];
        int c = ei[E + e];
        if (r != c) {
            int p = blockIdx.x & 7;
            int k = atomicAdd(&poff[p * N + r], 1);   // cursor = partition base + count
            int pos = row_ptr[r] + k;
            float w = -dinv[r] * dinv[c];
            e_cw[pos] = (unsigned)c | ((unsigned)f16b(w) << 16);
        }
    }
}

// ---------------- sparse prop (pure gather: hout = L_hat @ hin), XCD-sliced ----------------
// slice = blockIdx&7 -> one XCD per slice (1.6 MB table, L2-resident).
// 1 wave per (node, slice); lane = e5(5b edge-slot) x s(1b 16B half of the
// 32B slice row). 32 edge-slots/iter -> deg~16 fits one iteration. Metadata
// via ONE coalesced per-lane load (each value read by a lane pair). Pad
// slots gather node 0 (broadcast) with w=+0.0. Reduce via shfl_xor 2..32;
// lanes 0..1 store the 32B result.
__global__ __launch_bounds__(256) void prop_f16_kernel(
    const uint4* __restrict__ hin4, uint4* __restrict__ hout4,
    const int* __restrict__ row_ptr, const unsigned* __restrict__ e_cw, int n)
{
    int wv = __builtin_amdgcn_readfirstlane(threadIdx.x >> 6);
    const int sl = blockIdx.x & 7;           // slice -> XCD (round-robin dispatch)
    int node = (blockIdx.x >> 3) * 4 + wv;
    if (node >= n) return;
    const int lane = threadIdx.x & 63;
    const int e5 = lane >> 1;      // edge slot (0..31)
    const int s  = lane & 1;       // 16B half of 32B slice row
    int rs = row_ptr[node];
    int re = row_ptr[node + 1];
    const uint4* __restrict__ hsl = hin4 + (size_t)sl * n * 2;

    h2 a0 = (h2){(_Float16)0.f, (_Float16)0.f};
    h2 a1 = a0, a2 = a0, a3 = a0;

    for (int j = rs; j < re; j += 32) {
        int i0 = j + e5;
        unsigned cw = (i0 < re) ? e_cw[i0] : 0u;          // coalesced vector load
        h2 wp = f2h(__uint_as_float((cw & 0xffff0000u) | (cw >> 16)));
        uint4 v = hsl[(size_t)(cw & 0xffffu) * 2 + s];
        a0 = f2h(__uint_as_float(v.x)) * wp + a0;         // v_pk_fma_f16
        a1 = f2h(__uint_as_float(v.y)) * wp + a1;
        a2 = f2h(__uint_as_float(v.z)) * wp + a2;
        a3 = f2h(__uint_as_float(v.w)) * wp + a3;
    }
    // reduce across the 32 edge-slots (lane bits 1..5)
    #pragma unroll
    for (int off = 2; off < 64; off <<= 1) {
        a0 = a0 + f2h(__shfl_xor(h2f(a0), off));
        a1 = a1 + f2h(__shfl_xor(h2f(a1), off));
        a2 = a2 + f2h(__shfl_xor(h2f(a2), off));
        a3 = a3 + f2h(__shfl_xor(h2f(a3), off));
    }

    if (lane < 2) {
        uint4 o;
        o.x = __float_as_uint(h2f(a0));
        o.y = __float_as_uint(h2f(a1));
        o.z = __float_as_uint(h2f(a2));
        o.w = __float_as_uint(h2f(a3));
        hout4[((size_t)sl * n + node) * 2 + s] = o;
    }
}

// ---------------- fused 3-way MFMA GEMM (f16, XCD-sliced A) + bias + ReLU ----------------
#define WPAD 136
__global__ __launch_bounds__(256) void gemm3_mfma_kernel(
    const unsigned short* __restrict__ X0, const unsigned short* __restrict__ X1,
    const unsigned short* __restrict__ X2,
    const unsigned short* __restrict__ Wt, const float* __restrict__ bias,
    void* __restrict__ out, int n, int out_f16)
{
    __shared__ unsigned short Ws[DFEAT * WPAD];   // 34816 B
    const int t    = threadIdx.x;
    const int wave = t >> 6;
    const int lane = t & 63;
    const int quad = lane >> 4;
    const int l16  = lane & 15;

    const int row_base = blockIdx.x * 128 + wave * 32;
    int r0 = row_base + l16;       if (r0 >= n) r0 = n - 1;
    int r1 = row_base + 16 + l16;  if (r1 >= n) r1 = n - 1;

    const unsigned short* Xps[3] = {X0, X1, X2};

    f32x4 acc[2][8];
    #pragma unroll
    for (int tt = 0; tt < 2; ++tt)
        #pragma unroll
        for (int c = 0; c < 8; ++c) acc[tt][c] = (f32x4){0.f, 0.f, 0.f, 0.f};

    const int srow = t >> 1;            // staging: row 0..127
    const int shalf = (t & 1) * 64;     // half-row

    #pragma unroll
    for (int seg = 0; seg < 3; ++seg) {
        __syncthreads();   // previous seg fully consumed
        const unsigned short* Wp = Wt + (seg << 14);
        #pragma unroll
        for (int i = 0; i < 8; ++i) {
            *(u16x8*)&Ws[srow * WPAD + shalf + i * 8] =
                *(const u16x8*)&Wp[srow * DFEAT + shalf + i * 8];
        }
        __syncthreads();
        const unsigned short* Ab = Xps[seg];
        #pragma unroll
        for (int kk = 0; kk < 4; ++kk) {
            const int ko = kk * 32 + quad * 8;
            // sliced A: feature ko lives at slice ko>>4, offset ko&15
            const size_t sb = (size_t)(ko >> 4) * n * 16 + (ko & 15);
            f16x8 a0 = *(const f16x8*)(Ab + sb + (size_t)r0 * 16);
            f16x8 a1 = *(const f16x8*)(Ab + sb + (size_t)r1 * 16);
            #pragma unroll
            for (int c = 0; c < 8; ++c) {
                f16x8 b = *(const f16x8*)&Ws[(c * 16 + l16) * WPAD + ko];
                acc[0][c] = __builtin_amdgcn_mfma_f32_16x16x32_f16(a0, b, acc[0][c], 0, 0, 0);
                acc[1][c] = __builtin_amdgcn_mfma_f32_16x16x32_f16(a1, b, acc[1][c], 0, 0, 0);
            }
        }
    }

    // C/D layout: col = lane&15, row = quad*4 + reg
    #pragma unroll
    for (int tt = 0; tt < 2; ++tt) {
        int orow0 = blockIdx.x * 128 + wave * 32 + tt * 16 + quad * 4;
        #pragma unroll
        for (int c = 0; c < 8; ++c) {
            int col = c * 16 + l16;
            float bv = bias[col];
            #pragma unroll
            for (int r = 0; r < 4; ++r) {
                int orow = orow0 + r;
                if (orow < n) {
                    float v = fmaxf(acc[tt][c][r] + bv, 0.f);
                    if (out_f16) {
                        // sliced store: col = c*16 + l16 -> slice c, offset l16
                        ((unsigned short*)out)[((size_t)c * n + orow) * 16 + l16] = f16b(v);
                    } else {
                        ((float*)out)[(size_t)orow * DFEAT + col] = v;
                    }
                }
            }
        }
    }
}

extern "C" void kernel_launch(void* const* d_in, const int* in_sizes, int n_in,
                              void* d_out, int out_size, void* d_ws, size_t ws_size,
                              hipStream_t stream) {
    const float* x  = (const float*)d_in[0];
    const int*   ei = (const int*)d_in[1];
    const float* W1 = (const float*)d_in[2];
    const float* b1 = (const float*)d_in[3];
    const float* W2 = (const float*)d_in[4];
    const float* b2 = (const float*)d_in[5];
    const float* W3 = (const float*)d_in[6];
    const float* b3 = (const float*)d_in[7];

    const int N = in_sizes[0] / DFEAT;   // 50000
    const int E = in_sizes[1] / 2;       // 800000
    const int NPK = N * (DFEAT / 2);     // packed f16x2 words per array
    const int NB = (N + 1023) / 1024;    // scan blocks

    // workspace layout
    unsigned* xb  = (unsigned*)d_ws;
    unsigned* t1b = xb  + NPK;
    unsigned* t2b = t1b + NPK;
    unsigned* ab  = t2b + NPK;
    unsigned short* wt = (unsigned short*)(ab + NPK);   // 3 layers * 3*128*128
    int*   deg8    = (int*)(wt + 3 * 3 * DFEAT * DFEAT);
    int*   poff    = deg8 + 8 * N;
    int*   row_ptr = poff + 8 * N;
    float* dinv    = (float*)(row_ptr + (N + 2));
    unsigned* e_cw = (unsigned*)(dinv + N);
    int*   bsum    = (int*)(e_cw + E);

    const int WELEM = 3 * DFEAT * DFEAT;
    const int CONVT = NPK + 3 * WELEM;
    conv_kernel<<<(CONVT + 255) / 256, 256, 0, stream>>>(
        (const float2*)x, xb, NPK, W1, W2, W3, wt, deg8, N);
    deg_kernel<<<(E + 255) / 256, 256, 0, stream>>>(ei, deg8, E, N);
    scan1_kernel<<<NB, 1024, 0, stream>>>(deg8, poff, row_ptr, bsum, dinv, N);
    scan3_kernel<<<NB, 1024, 0, stream>>>(row_ptr, bsum, N);
    fill_kernel<<<(E + 255) / 256, 256, 0, stream>>>(ei, row_ptr, poff, dinv, e_cw, E, N);

    const float* bl[3] = {b1, b2, b3};
    const unsigned* hin = xb;
    const int prop_grid = ((N + 3) / 4) * 8;   // 8 concurrent slices
    const int gemm_grid = (N + 127) / 128;
    for (int l = 0; l < 3; ++l) {
        // Tx1 = L_hat @ h
        prop_f16_kernel<<<prop_grid, 256, 0, stream>>>(
            (const uint4*)hin, (uint4*)t1b, row_ptr, e_cw, N);
        // P = L_hat @ Tx1   (2P - h folded into weights)
        prop_f16_kernel<<<prop_grid, 256, 0, stream>>>(
            (const uint4*)t1b, (uint4*)t2b, row_ptr, e_cw, N);
        // out = relu(h@(W0-W2) + Tx1@W1 + P@(2W2) + b)
        void* hout = (l == 2) ? d_out : (void*)ab;
        gemm3_mfma_kernel<<<gemm_grid, 256, 0, stream>>>(
            (const unsigned short*)hin, (const unsigned short*)t1b, (const unsigned short*)t2b,
            wt + l * WELEM, bl[l], hout, N, (l == 2) ? 0 : 1);
        hin = ab;
    }
}